// Round 3
// baseline (909.558 us; speedup 1.0000x reference)
//
#include <hip/hip_runtime.h>
#include <hip/hip_bf16.h>

#define EMBED 1024
#define TSEQ  1024
#define NB    16
#define NH    16
#define HD    64
#define MROWS (NB * TSEQ)   // 16384

typedef __bf16 bf16x8 __attribute__((ext_vector_type(8)));
typedef float  f32x4  __attribute__((ext_vector_type(4)));

// float -> bf16 bits, round-to-nearest-even (finite inputs only)
__device__ __forceinline__ unsigned int f2bf_bits(float x) {
    union { float f; unsigned int u; } v; v.f = x;
    unsigned int r = v.u + 0x7FFFu + ((v.u >> 16) & 1u);
    return r >> 16;
}

// ---------------------------------------------------------------------------
// Input-dtype sniff (proven in prior session): bits[14:7] of u32 words of X
// are the low bf16's exponent byte if packed-bf16 (~always in [100,150] for
// N(0,1)), but mid-mantissa bits (~uniform) if f32.
// ---------------------------------------------------------------------------
__device__ __forceinline__ int detect_bf16(const unsigned int* __restrict__ X) {
    __shared__ int s_cnt;
    if (threadIdx.x == 0) s_cnt = 0;
    __syncthreads();
    int c = 0;
    const int base = threadIdx.x * 16;
#pragma unroll
    for (int i = 0; i < 16; ++i) {
        unsigned int e = (X[base + i] >> 7) & 0xFFu;
        c += (e >= 100u && e <= 150u) ? 1 : 0;
    }
    atomicAdd(&s_cnt, c);
    __syncthreads();
    return s_cnt >= 2458;   // 0.6 * 4096
}

__device__ __forceinline__ uint4 load8(const void* __restrict__ p, size_t eoff,
                                       int is_bf16) {
    if (is_bf16) {
        return *(const uint4*)((const __hip_bfloat16*)p + eoff);
    }
    const float* f = (const float*)p + eoff;
    float4 a = *(const float4*)f;
    float4 b = *(const float4*)(f + 4);
    uint4 r;
    r.x = f2bf_bits(a.x) | (f2bf_bits(a.y) << 16);
    r.y = f2bf_bits(a.z) | (f2bf_bits(a.w) << 16);
    r.z = f2bf_bits(b.x) | (f2bf_bits(b.y) << 16);
    r.w = f2bf_bits(b.z) | (f2bf_bits(b.w) << 16);
    return r;
}

// async global->LDS, 16B per lane (dest must be linear: base + lane*16)
__device__ __forceinline__ void gload16(const __hip_bfloat16* g,
                                        __hip_bfloat16* l) {
    __builtin_amdgcn_global_load_lds(
        (const __attribute__((address_space(1))) void*)g,
        (__attribute__((address_space(3))) void*)l, 16, 0, 0);
}

// ---------------------------------------------------------------------------
// One-time dtype normalization: src (f32 or bf16, sniffed) -> bf16 dst.
// ---------------------------------------------------------------------------
__global__ __launch_bounds__(256) void to_bf16(
    const void* __restrict__ src, __hip_bfloat16* __restrict__ dst,
    int n8, const unsigned int* __restrict__ det)
{
    const int isbf = detect_bf16(det);
    const int i = blockIdx.x * 256 + threadIdx.x;
    if (i < n8) *(uint4*)(dst + (size_t)i * 8) = load8(src, (size_t)i * 8, isbf);
}

// ---------------------------------------------------------------------------
// Mask int32 -> bitmask (1 bit per element). Wave-wide ballot, 2 stores/wave.
// Word w of bm covers mask flat indices [32w, 32w+32).
// ---------------------------------------------------------------------------
__global__ __launch_bounds__(256) void pack_mask(
    const int* __restrict__ m, unsigned* __restrict__ bm, int n)
{
    const int i = blockIdx.x * 256 + threadIdx.x;
    const unsigned long long bal = __ballot(i < n && m[i] != 0);
    if ((threadIdx.x & 31) == 0 && i < n) {
        bm[i >> 5] = (unsigned)(((threadIdx.x & 63) < 32) ? bal : (bal >> 32));
    }
}

// ---------------------------------------------------------------------------
// C[m][n] = cscale * sum_k A[m][k] * W[n][k]  (+ bias[n])
// 128x128 tile, BK=32, 256 thr (4 waves), 16x16x32 bf16 MFMA, 4x4/wave.
// AD/BD template: 1 = operand is known bf16 -> global_load_lds staging
// (linear LDS, pitch 32); 0 = flex f32/bf16 reg staging (pitch 40, padded).
// out_mode: 0 = bf16 C[m][n]; 1 = detected-dtype C[m][n] (final output);
//           2 = bf16 transposed per-head layout Vt[b][h][d][t] (for PV MFMA).
// ---------------------------------------------------------------------------
#define BK  32
#define LDK 40

template<int AD, int BD>
__global__ __launch_bounds__(256) void gemm_t(
    const void* __restrict__ A,
    const void* __restrict__ W,
    void* __restrict__ C,
    const void* __restrict__ bias,
    const unsigned int* __restrict__ Xdet,
    int a_flex, int out_mode, float cscale)
{
    const int isbf = detect_bf16(Xdet);
    const int a_bf = a_flex ? isbf : 1;

    constexpr int LA = AD ? BK : LDK;
    constexpr int LB = BD ? BK : LDK;
    __shared__ __hip_bfloat16 As[128 * LA];
    __shared__ __hip_bfloat16 Bs[128 * LB];

    const int tid  = threadIdx.x;
    const int lane = tid & 63;
    const int w    = tid >> 6;
    const int wm   = w & 1;
    const int wn   = w >> 1;
    const int m0   = blockIdx.x * 128;
    const int n0   = blockIdx.y * 128;

    const int r0 = tid >> 2;             // 0..63
    const int c0 = (tid & 3) * 8;        // 0,8,16,24

    f32x4 acc[4][4];
#pragma unroll
    for (int i = 0; i < 4; ++i)
#pragma unroll
        for (int j = 0; j < 4; ++j)
            acc[i][j] = (f32x4){0.f, 0.f, 0.f, 0.f};

    const int fr = lane & 15;
    const int fq = lane >> 4;

    for (int k0 = 0; k0 < EMBED; k0 += BK) {
        uint4 ra0, ra1, rb0, rb1;
        if constexpr (!AD) {
            ra0 = load8(A, (size_t)(m0 + r0)      * EMBED + c0 + k0, a_bf);
            ra1 = load8(A, (size_t)(m0 + r0 + 64) * EMBED + c0 + k0, a_bf);
        }
        if constexpr (!BD) {
            rb0 = load8(W, (size_t)(n0 + r0)      * EMBED + c0 + k0, isbf);
            rb1 = load8(W, (size_t)(n0 + r0 + 64) * EMBED + c0 + k0, isbf);
        }
        __syncthreads();
        if constexpr (AD) {
            const __hip_bfloat16* Ab =
                (const __hip_bfloat16*)A + (size_t)(m0 + r0) * EMBED + c0 + k0;
            gload16(Ab,                      &As[tid * 8]);
            gload16(Ab + (size_t)64 * EMBED, &As[64 * BK + tid * 8]);
        } else {
            *(uint4*)&As[r0 * LA + c0]        = ra0;
            *(uint4*)&As[(r0 + 64) * LA + c0] = ra1;
        }
        if constexpr (BD) {
            const __hip_bfloat16* Wp =
                (const __hip_bfloat16*)W + (size_t)(n0 + r0) * EMBED + c0 + k0;
            gload16(Wp,                      &Bs[tid * 8]);
            gload16(Wp + (size_t)64 * EMBED, &Bs[64 * BK + tid * 8]);
        } else {
            *(uint4*)&Bs[r0 * LB + c0]        = rb0;
            *(uint4*)&Bs[(r0 + 64) * LB + c0] = rb1;
        }
        __syncthreads();

        bf16x8 af[4], bfr[4];
#pragma unroll
        for (int i = 0; i < 4; ++i) {
            af[i]  = *(const bf16x8*)&As[(wm * 64 + i * 16 + fr) * LA + fq * 8];
            bfr[i] = *(const bf16x8*)&Bs[(wn * 64 + i * 16 + fr) * LB + fq * 8];
        }
#pragma unroll
        for (int i = 0; i < 4; ++i)
#pragma unroll
            for (int j = 0; j < 4; ++j)
                acc[i][j] = __builtin_amdgcn_mfma_f32_16x16x32_bf16(
                    af[i], bfr[j], acc[i][j], 0, 0, 0);
    }

    float bv[4] = {0.f, 0.f, 0.f, 0.f};
    if (bias != nullptr) {
#pragma unroll
        for (int j = 0; j < 4; ++j) {
            const int idx = n0 + wn * 64 + j * 16 + fr;
            bv[j] = isbf ? __bfloat162float(((const __hip_bfloat16*)bias)[idx])
                         : ((const float*)bias)[idx];
        }
    }

    if (out_mode == 2) {
        // Vt[b][h][d][t]: C-layout regs r=0..3 are 4 consecutive t -> uint2
#pragma unroll
        for (int i = 0; i < 4; ++i) {
            const int row = m0 + wm * 64 + i * 16 + fq * 4;   // token (base)
            const int bb = row >> 10, tt = row & 1023;
#pragma unroll
            for (int j = 0; j < 4; ++j) {
                const int col = n0 + wn * 64 + j * 16 + fr;   // channel
                const int hh = col >> 6, dd = col & 63;
                uint2 st;
                st.x = f2bf_bits(acc[i][j][0] * cscale) |
                       (f2bf_bits(acc[i][j][1] * cscale) << 16);
                st.y = f2bf_bits(acc[i][j][2] * cscale) |
                       (f2bf_bits(acc[i][j][3] * cscale) << 16);
                *(uint2*)&((__hip_bfloat16*)C)[
                    (((size_t)(bb * NH + hh) * HD + dd) * TSEQ) + tt] = st;
            }
        }
        return;
    }

    const int c_bf = (out_mode == 1) ? isbf : 1;
#pragma unroll
    for (int i = 0; i < 4; ++i) {
        const int row = m0 + wm * 64 + i * 16 + fq * 4;
#pragma unroll
        for (int j = 0; j < 4; ++j) {
            const int col = n0 + wn * 64 + j * 16 + fr;
#pragma unroll
            for (int r = 0; r < 4; ++r) {
                const size_t off = (size_t)(row + r) * EMBED + col;
                const float v = acc[i][j][r] * cscale + bv[j];
                if (c_bf) ((__hip_bfloat16*)C)[off] = __float2bfloat16(v);
                else      ((float*)C)[off] = v;
            }
        }
    }
}

// ---------------------------------------------------------------------------
// MFMA flash attention, barrier-free. Block = 256 thr (4 waves) x 64 queries
// (16 q/wave); 8 KV-tiles of 128 keys. Q A-frags in regs (Q pre-scaled by
// log2e/sqrt(E) in the Q-projection epilogue -> softmax in exp2 domain).
// Masked scores -1e30; running max starts at -1e29 so exp2 underflows to 0.
//
// R3: NO K/V LDS staging. K/V tiles per (b,h) are 128 KB each, shared by 16
// blocks -> L2-resident; staging them was pure overhead (and the barriers it
// required were the main stall). B-fragments are read directly from global;
// the only LDS is the per-wave P transpose buffer (wave-synchronous, so the
// kernel has ZERO __syncthreads in the loop). Occupancy cap 4 blocks/CU.
// ---------------------------------------------------------------------------
#define QT  64
#define KTL 128
#define NT  (TSEQ / KTL)   // 8
#define PP  136   // Ps pitch: per wave [16 q][128 keys + 8 pad]

__global__ __launch_bounds__(256, 4) void attn_mfma(
    const __hip_bfloat16* __restrict__ Q,
    const __hip_bfloat16* __restrict__ K,
    const __hip_bfloat16* __restrict__ Vt,
    const int* __restrict__ mask,
    const unsigned* __restrict__ bmask,
    __hip_bfloat16* __restrict__ O)
{
    __shared__ __hip_bfloat16 Ps[4][16 * PP];

    const int tid  = threadIdx.x;
    const int lane = tid & 63;
    const int w    = tid >> 6;
    const int fr   = lane & 15;
    const int fq   = lane >> 4;
    const int qb = blockIdx.x, h = blockIdx.y, b = blockIdx.z;
    const int q0 = qb * QT;

    // Q A-frags: A[m = lane&15][k = fq*8 + j], k-chunks 0 and 32
    const __hip_bfloat16* qptr =
        Q + (size_t)(b * TSEQ + q0 + w * 16 + fr) * EMBED + h * HD + fq * 8;
    const bf16x8 qa0 = *(const bf16x8*)qptr;
    const bf16x8 qa1 = *(const bf16x8*)(qptr + 32);

    // per-lane fixed parts of the K / V fragment addresses
    // K frag (tile kt, sub t): row = kt*KTL + t*16 + fr, col = fq*8 (+32)
    const __hip_bfloat16* kq =
        K + ((size_t)(b * TSEQ) + fr) * EMBED + h * HD + fq * 8;
    // V frag (tile kt, sub dt,kc): row = dt*16 + fr, col = kt*KTL + kc*32 + fq*8
    const __hip_bfloat16* vq =
        Vt + ((size_t)(b * NH + h) * HD + fr) * TSEQ + fq * 8;

    // bitmask row base (words; row = b*TSEQ + q0 + w*16 + fq*4 + r)
    const unsigned* bmbase = bmask
        ? bmask + (size_t)(b * TSEQ + q0 + w * 16 + fq * 4) * (TSEQ / 32)
        : nullptr;

    float mS[4], lS[4];
    f32x4 oacc[4];
#pragma unroll
    for (int r = 0; r < 4; ++r) { mS[r] = -1e29f; lS[r] = 0.f; }
#pragma unroll
    for (int dt = 0; dt < 4; ++dt) oacc[dt] = (f32x4){0.f, 0.f, 0.f, 0.f};

    for (int kt = 0; kt < NT; ++kt) {
        // mask words: 4 broadcast uint4 loads (bitmask) or legacy int loads
        uint4 mw[4];
        int mvf[8][4];
        if (bmask) {
#pragma unroll
            for (int r = 0; r < 4; ++r)
                mw[r] = *(const uint4*)(bmbase + (size_t)r * (TSEQ / 32) + kt * 4);
        } else {
            const int* mbase = mask +
                (size_t)(b * TSEQ + q0 + w * 16 + fq * 4) * TSEQ + kt * KTL + fr;
#pragma unroll
            for (int t = 0; t < 8; ++t)
#pragma unroll
                for (int r = 0; r < 4; ++r)
                    mvf[t][r] = mbase[r * TSEQ + t * 16];
        }

        // QK^T: S[16 q][128 keys] in 8 C-layout frags (exp2 domain); K frags
        // straight from global (L2-resident tile)
        const __hip_bfloat16* kt_ptr = kq + (size_t)(kt * KTL) * EMBED;
        f32x4 s[8];
#pragma unroll
        for (int t = 0; t < 8; ++t) {
            const bf16x8 kb0 = *(const bf16x8*)(kt_ptr + (size_t)(t * 16) * EMBED);
            const bf16x8 kb1 = *(const bf16x8*)(kt_ptr + (size_t)(t * 16) * EMBED + 32);
            s[t] = __builtin_amdgcn_mfma_f32_16x16x32_bf16(
                qa0, kb0, (f32x4){0.f, 0.f, 0.f, 0.f}, 0, 0, 0);
            s[t] = __builtin_amdgcn_mfma_f32_16x16x32_bf16(qa1, kb1, s[t], 0, 0, 0);
        }

        // mask (scale already folded into Q)
        if (bmask) {
#pragma unroll
            for (int t = 0; t < 8; ++t)
#pragma unroll
                for (int r = 0; r < 4; ++r) {
                    const unsigned wv = ((const unsigned*)&mw[r])[t >> 1] >> fr;
                    if (((wv >> ((t & 1) * 16)) & 1u) == 0u) s[t][r] = -1e30f;
                }
        } else {
#pragma unroll
            for (int t = 0; t < 8; ++t)
#pragma unroll
                for (int r = 0; r < 4; ++r)
                    if (mvf[t][r] == 0) s[t][r] = -1e30f;
        }

        // online softmax per row (row = fq*4 + r; 16 cols/lane-group x 8 frags)
#pragma unroll
        for (int r = 0; r < 4; ++r) {
            float mx = s[0][r];
#pragma unroll
            for (int t = 1; t < 8; ++t) mx = fmaxf(mx, s[t][r]);
#pragma unroll
            for (int off = 8; off > 0; off >>= 1) mx = fmaxf(mx, __shfl_xor(mx, off));
            const float mnew  = fmaxf(mS[r], mx);
            const float alpha = __builtin_amdgcn_exp2f(mS[r] - mnew);
            mS[r] = mnew;
            float ls = 0.f;
#pragma unroll
            for (int t = 0; t < 8; ++t) {
                const float p = __builtin_amdgcn_exp2f(s[t][r] - mnew);
                s[t][r] = p;
                ls += p;
            }
#pragma unroll
            for (int off = 8; off > 0; off >>= 1) ls += __shfl_xor(ls, off);
            lS[r] = lS[r] * alpha + ls;
#pragma unroll
            for (int dt = 0; dt < 4; ++dt) oacc[dt][r] *= alpha;
        }

        // P -> per-wave LDS (C-layout scatter), then A-layout b128 reads.
        // Wave-synchronous: no barrier needed (compiler inserts lgkmcnt).
#pragma unroll
        for (int t = 0; t < 8; ++t)
#pragma unroll
            for (int r = 0; r < 4; ++r)
                Ps[w][(fq * 4 + r) * PP + t * 16 + fr] = __float2bfloat16(s[t][r]);

        // PV: O[16 q][64 d] += P[16][128] x V[128][64]; V frags from global
        const __hip_bfloat16* vt_ptr = vq + kt * KTL;
#pragma unroll
        for (int kc = 0; kc < 4; ++kc) {
            const bf16x8 pa = *(const bf16x8*)&Ps[w][fr * PP + kc * 32 + fq * 8];
#pragma unroll
            for (int dt = 0; dt < 4; ++dt) {
                const bf16x8 vb = *(const bf16x8*)(
                    vt_ptr + (size_t)(dt * 16) * TSEQ + kc * 32);
                oacc[dt] = __builtin_amdgcn_mfma_f32_16x16x32_bf16(
                    pa, vb, oacc[dt], 0, 0, 0);
            }
        }
    }

    // epilogue: normalize, write O (in place over Q; block owns its slice)
    float inv[4];
#pragma unroll
    for (int r = 0; r < 4; ++r) inv[r] = 1.f / fmaxf(lS[r], 1e-30f);
#pragma unroll
    for (int dt = 0; dt < 4; ++dt)
#pragma unroll
        for (int r = 0; r < 4; ++r)
            O[(size_t)(b * TSEQ + q0 + w * 16 + fq * 4 + r) * EMBED
              + h * HD + dt * 16 + fr] = __float2bfloat16(oacc[dt][r] * inv[r]);
}

// ---------------------------------------------------------------------------
// Memory plan:
//   ws:    [Q | K] bf16 (64 MiB) | optional Wb[4] bf16 (8 MiB) | (bm spill)
//   d_out: [Vt bf16 32 MiB | Xb bf16 32 MiB]; after the V-GEMM Xb is dead and
//          pack_mask reuses its first 2 MiB for the bitmask. Final GEMM
//          overwrites d_out with the f32 result.
// ---------------------------------------------------------------------------
static inline void launch_gemm(int ad, int bd, dim3 g, dim3 b, hipStream_t s,
                               const void* A, const void* W, void* C,
                               const void* bias, const unsigned int* Xdet,
                               int a_flex, int out_mode, float cs)
{
    if (ad && bd)
        gemm_t<1, 1><<<g, b, 0, s>>>(A, W, C, bias, Xdet, a_flex, out_mode, cs);
    else if (ad)
        gemm_t<1, 0><<<g, b, 0, s>>>(A, W, C, bias, Xdet, a_flex, out_mode, cs);
    else if (bd)
        gemm_t<0, 1><<<g, b, 0, s>>>(A, W, C, bias, Xdet, a_flex, out_mode, cs);
    else
        gemm_t<0, 0><<<g, b, 0, s>>>(A, W, C, bias, Xdet, a_flex, out_mode, cs);
}

extern "C" void kernel_launch(void* const* d_in, const int* in_sizes, int n_in,
                              void* d_out, int out_size, void* d_ws, size_t ws_size,
                              hipStream_t stream) {
    const void* X  = d_in[0];
    const int*  Mk = (const int*)d_in[1];
    const void* Wsrc[4] = { d_in[2], d_in[3], d_in[4], d_in[5] };
    const void* bo = d_in[6];
    const unsigned int* Xdet = (const unsigned int*)d_in[0];

    const size_t n_elem = (size_t)MROWS * EMBED;    // 16 Mi elems
    const size_t w_elem = (size_t)EMBED * EMBED;    // 1 Mi elems
    __hip_bfloat16* Qb  = (__hip_bfloat16*)d_ws;    // ws: Q | K
    __hip_bfloat16* Kb  = Qb + n_elem;
    __hip_bfloat16* Vtb = (__hip_bfloat16*)d_out;   // V^T in d_out lower half
    size_t ws_used = 2 * n_elem * sizeof(__hip_bfloat16);

    dim3 blk(256);

    // --- A operand (X): normalize to bf16 once if we have room ---
    const void* Ax = X;
    int ad = 0;
    if (in_sizes[0] == (int)(n_elem * 2)) {
        ad = 1;                                      // already bf16-sized
    } else {
        __hip_bfloat16* Xb = nullptr;
        if ((size_t)out_size >= n_elem * 4) {
            Xb = (__hip_bfloat16*)d_out + n_elem;    // d_out upper half
        } else if (ws_size >= ws_used + n_elem * 2) {
            Xb = (__hip_bfloat16*)((char*)d_ws + ws_used);
            ws_used += n_elem * 2;
        }
        if (Xb) {
            to_bf16<<<dim3((unsigned)(n_elem / 8 / 256)), blk, 0, stream>>>(
                X, Xb, (int)(n_elem / 8), Xdet);
            Ax = Xb;
            ad = 1;
        }
    }

    // --- B operands (W): normalize to bf16 once if ws has room ---
    const void* Wb[4];
    int bd = 0;
    if (in_sizes[2] == (int)(w_elem * 2)) {
        for (int i = 0; i < 4; ++i) Wb[i] = Wsrc[i];
        bd = 1;
    } else if (ws_size >= ws_used + 4 * w_elem * 2) {
        __hip_bfloat16* p = (__hip_bfloat16*)((char*)d_ws + ws_used);
        for (int i = 0; i < 4; ++i) {
            to_bf16<<<dim3((unsigned)(w_elem / 8 / 256)), blk, 0, stream>>>(
                Wsrc[i], p + (size_t)i * w_elem, (int)(w_elem / 8), Xdet);
            Wb[i] = p + (size_t)i * w_elem;
        }
        ws_used += 4 * w_elem * 2;
        bd = 1;
    } else {
        for (int i = 0; i < 4; ++i) Wb[i] = Wsrc[i];
    }

    // --- bitmask buffer: dead-Xb region of d_out, else ws tail ---
    const size_t bm_words = (size_t)NB * TSEQ * (TSEQ / 32);   // 512 Ki words
    const size_t bm_bytes = bm_words * 4;                      // 2 MiB
    unsigned* bm = nullptr;
    if ((size_t)out_size >= n_elem * 2 + bm_bytes) {
        bm = (unsigned*)((char*)d_out + n_elem * 2);           // dead-Xb start
    } else if (ws_size >= ws_used + bm_bytes) {
        bm = (unsigned*)((char*)d_ws + ws_used);
        ws_used += bm_bytes;
    }

    dim3 gg(MROWS / 128, EMBED / 128, 1);
    // fold softmax scale (1/sqrt(1024)) * log2(e) into Q projection
    const float qs = 0.03125f * 1.44269504088896f;
    launch_gemm(ad, bd, gg, blk, stream, Ax, Wb[0], Qb,  nullptr, Xdet, 1, 0, qs);
    launch_gemm(ad, bd, gg, blk, stream, Ax, Wb[1], Kb,  nullptr, Xdet, 1, 0, 1.f);
    launch_gemm(ad, bd, gg, blk, stream, Ax, Wb[2], Vtb, nullptr, Xdet, 1, 2, 1.f);

    // pack mask AFTER the V-GEMM (it overwrites the start of dead Xb)
    if (bm) {
        const int nmask = NB * TSEQ * TSEQ;                    // 16.7M
        pack_mask<<<dim3(nmask / 256), blk, 0, stream>>>(Mk, bm, nmask);
    }

    dim3 ga(TSEQ / QT, NH, NB);                      // 16 x 16 x 16
    attn_mfma<<<ga, blk, 0, stream>>>(Qb, Kb, Vtb, Mk, bm, Qb);

    // final GEMM: A = attention output (bf16 in ws) -> always direct
    launch_gemm(1, bd, gg, blk, stream, Qb, Wb[3], d_out, bo, Xdet, 0, 1, 1.f);
}

// Round 4
// 653.355 us; speedup vs baseline: 1.3921x; 1.3921x over previous
//
#include <hip/hip_runtime.h>
#include <hip/hip_bf16.h>

#define EMBED 1024
#define TSEQ  1024
#define NB    16
#define NH    16
#define HD    64
#define MROWS (NB * TSEQ)   // 16384

typedef __bf16 bf16x8 __attribute__((ext_vector_type(8)));
typedef float  f32x4  __attribute__((ext_vector_type(4)));

// float -> bf16 bits, round-to-nearest-even (finite inputs only)
__device__ __forceinline__ unsigned int f2bf_bits(float x) {
    union { float f; unsigned int u; } v; v.f = x;
    unsigned int r = v.u + 0x7FFFu + ((v.u >> 16) & 1u);
    return r >> 16;
}

// ---------------------------------------------------------------------------
// Input-dtype sniff (proven): bits[14:7] of u32 words of X are the low bf16's
// exponent byte if packed-bf16 (~always in [100,150] for N(0,1)), but
// mid-mantissa bits (~uniform) if f32.
// ---------------------------------------------------------------------------
__device__ __forceinline__ int detect_bf16(const unsigned int* __restrict__ X) {
    __shared__ int s_cnt;
    if (threadIdx.x == 0) s_cnt = 0;
    __syncthreads();
    int c = 0;
    const int base = threadIdx.x * 16;
#pragma unroll
    for (int i = 0; i < 16; ++i) {
        unsigned int e = (X[base + i] >> 7) & 0xFFu;
        c += (e >= 100u && e <= 150u) ? 1 : 0;
    }
    atomicAdd(&s_cnt, c);
    __syncthreads();
    return s_cnt >= 2458;   // 0.6 * 4096
}

__device__ __forceinline__ uint4 load8(const void* __restrict__ p, size_t eoff,
                                       int is_bf16) {
    if (is_bf16) {
        return *(const uint4*)((const __hip_bfloat16*)p + eoff);
    }
    const float* f = (const float*)p + eoff;
    float4 a = *(const float4*)f;
    float4 b = *(const float4*)(f + 4);
    uint4 r;
    r.x = f2bf_bits(a.x) | (f2bf_bits(a.y) << 16);
    r.y = f2bf_bits(a.z) | (f2bf_bits(a.w) << 16);
    r.z = f2bf_bits(b.x) | (f2bf_bits(b.y) << 16);
    r.w = f2bf_bits(b.z) | (f2bf_bits(b.w) << 16);
    return r;
}

// async global->LDS, 16B per lane (dest must be linear: base + lane*16)
__device__ __forceinline__ void gload16(const __hip_bfloat16* g,
                                        __hip_bfloat16* l) {
    __builtin_amdgcn_global_load_lds(
        (const __attribute__((address_space(1))) void*)g,
        (__attribute__((address_space(3))) void*)l, 16, 0, 0);
}

// ---------------------------------------------------------------------------
// One-time dtype normalization: src (f32 or bf16, sniffed) -> bf16 dst.
// ---------------------------------------------------------------------------
__global__ __launch_bounds__(256) void to_bf16(
    const void* __restrict__ src, __hip_bfloat16* __restrict__ dst,
    int n8, const unsigned int* __restrict__ det)
{
    const int isbf = detect_bf16(det);
    const int i = blockIdx.x * 256 + threadIdx.x;
    if (i < n8) *(uint4*)(dst + (size_t)i * 8) = load8(src, (size_t)i * 8, isbf);
}

// ---------------------------------------------------------------------------
// Mask int32 -> bitmask (1 bit per element). Wave-wide ballot, 2 stores/wave.
// Word w of bm covers mask flat indices [32w, 32w+32).
// ---------------------------------------------------------------------------
__global__ __launch_bounds__(256) void pack_mask(
    const int* __restrict__ m, unsigned* __restrict__ bm, int n)
{
    const int i = blockIdx.x * 256 + threadIdx.x;
    const unsigned long long bal = __ballot(i < n && m[i] != 0);
    if ((threadIdx.x & 31) == 0 && i < n) {
        bm[i >> 5] = (unsigned)(((threadIdx.x & 63) < 32) ? bal : (bal >> 32));
    }
}

// ---------------------------------------------------------------------------
// C[m][n] = cscale * sum_k A[m][k] * W[n][k]  (+ bias[n])
// 128x128 tile, BK=32, 256 thr (4 waves), 16x16x32 bf16 MFMA, 4x4/wave.
// Grid: x = n-tile (8), y = m-tile (128) -> consecutive blocks share the
// A-panel (read once from HBM) and stream the small W panels through L2.
// AD/BD template: 1 = operand is known bf16 -> global_load_lds staging
// (linear LDS, pitch 32); 0 = flex f32/bf16 reg staging (pitch 40, padded).
// out_mode: 0 = bf16 C[m][n]; 1 = detected-dtype C[m][n] (final output);
//           2 = bf16 transposed per-head layout Vt[b][h][d][t] (for PV MFMA).
// ---------------------------------------------------------------------------
#define BK  32
#define LDK 40

template<int AD, int BD>
__global__ __launch_bounds__(256) void gemm_t(
    const void* __restrict__ A,
    const void* __restrict__ W,
    void* __restrict__ C,
    const void* __restrict__ bias,
    const unsigned int* __restrict__ Xdet,
    int a_flex, int out_mode, float cscale)
{
    const int isbf = detect_bf16(Xdet);
    const int a_bf = a_flex ? isbf : 1;

    constexpr int LA = AD ? BK : LDK;
    constexpr int LB = BD ? BK : LDK;
    __shared__ __hip_bfloat16 As[128 * LA];
    __shared__ __hip_bfloat16 Bs[128 * LB];

    const int tid  = threadIdx.x;
    const int lane = tid & 63;
    const int w    = tid >> 6;
    const int wm   = w & 1;
    const int wn   = w >> 1;
    const int m0   = blockIdx.y * 128;   // m-tile on y (128 of them)
    const int n0   = blockIdx.x * 128;   // n-tile on x (8 of them)

    const int r0 = tid >> 2;             // 0..63
    const int c0 = (tid & 3) * 8;        // 0,8,16,24

    f32x4 acc[4][4];
#pragma unroll
    for (int i = 0; i < 4; ++i)
#pragma unroll
        for (int j = 0; j < 4; ++j)
            acc[i][j] = (f32x4){0.f, 0.f, 0.f, 0.f};

    const int fr = lane & 15;
    const int fq = lane >> 4;

    for (int k0 = 0; k0 < EMBED; k0 += BK) {
        uint4 ra0, ra1, rb0, rb1;
        if constexpr (!AD) {
            ra0 = load8(A, (size_t)(m0 + r0)      * EMBED + c0 + k0, a_bf);
            ra1 = load8(A, (size_t)(m0 + r0 + 64) * EMBED + c0 + k0, a_bf);
        }
        if constexpr (!BD) {
            rb0 = load8(W, (size_t)(n0 + r0)      * EMBED + c0 + k0, isbf);
            rb1 = load8(W, (size_t)(n0 + r0 + 64) * EMBED + c0 + k0, isbf);
        }
        __syncthreads();
        if constexpr (AD) {
            const __hip_bfloat16* Ab =
                (const __hip_bfloat16*)A + (size_t)(m0 + r0) * EMBED + c0 + k0;
            gload16(Ab,                      &As[tid * 8]);
            gload16(Ab + (size_t)64 * EMBED, &As[64 * BK + tid * 8]);
        } else {
            *(uint4*)&As[r0 * LA + c0]        = ra0;
            *(uint4*)&As[(r0 + 64) * LA + c0] = ra1;
        }
        if constexpr (BD) {
            const __hip_bfloat16* Wp =
                (const __hip_bfloat16*)W + (size_t)(n0 + r0) * EMBED + c0 + k0;
            gload16(Wp,                      &Bs[tid * 8]);
            gload16(Wp + (size_t)64 * EMBED, &Bs[64 * BK + tid * 8]);
        } else {
            *(uint4*)&Bs[r0 * LB + c0]        = rb0;
            *(uint4*)&Bs[(r0 + 64) * LB + c0] = rb1;
        }
        __syncthreads();

        bf16x8 af[4], bfr[4];
#pragma unroll
        for (int i = 0; i < 4; ++i) {
            af[i]  = *(const bf16x8*)&As[(wm * 64 + i * 16 + fr) * LA + fq * 8];
            bfr[i] = *(const bf16x8*)&Bs[(wn * 64 + i * 16 + fr) * LB + fq * 8];
        }
#pragma unroll
        for (int i = 0; i < 4; ++i)
#pragma unroll
            for (int j = 0; j < 4; ++j)
                acc[i][j] = __builtin_amdgcn_mfma_f32_16x16x32_bf16(
                    af[i], bfr[j], acc[i][j], 0, 0, 0);
    }

    float bv[4] = {0.f, 0.f, 0.f, 0.f};
    if (bias != nullptr) {
#pragma unroll
        for (int j = 0; j < 4; ++j) {
            const int idx = n0 + wn * 64 + j * 16 + fr;
            bv[j] = isbf ? __bfloat162float(((const __hip_bfloat16*)bias)[idx])
                         : ((const float*)bias)[idx];
        }
    }

    if (out_mode == 2) {
        // Vt[b][h][d][t]: C-layout regs r=0..3 are 4 consecutive t -> uint2
#pragma unroll
        for (int i = 0; i < 4; ++i) {
            const int row = m0 + wm * 64 + i * 16 + fq * 4;   // token (base)
            const int bb = row >> 10, tt = row & 1023;
#pragma unroll
            for (int j = 0; j < 4; ++j) {
                const int col = n0 + wn * 64 + j * 16 + fr;   // channel
                const int hh = col >> 6, dd = col & 63;
                uint2 st;
                st.x = f2bf_bits(acc[i][j][0] * cscale) |
                       (f2bf_bits(acc[i][j][1] * cscale) << 16);
                st.y = f2bf_bits(acc[i][j][2] * cscale) |
                       (f2bf_bits(acc[i][j][3] * cscale) << 16);
                *(uint2*)&((__hip_bfloat16*)C)[
                    (((size_t)(bb * NH + hh) * HD + dd) * TSEQ) + tt] = st;
            }
        }
        return;
    }

    const int c_bf = (out_mode == 1) ? isbf : 1;
#pragma unroll
    for (int i = 0; i < 4; ++i) {
        const int row = m0 + wm * 64 + i * 16 + fq * 4;
#pragma unroll
        for (int j = 0; j < 4; ++j) {
            const int col = n0 + wn * 64 + j * 16 + fr;
#pragma unroll
            for (int r = 0; r < 4; ++r) {
                const size_t off = (size_t)(row + r) * EMBED + col;
                const float v = acc[i][j][r] * cscale + bv[j];
                if (c_bf) ((__hip_bfloat16*)C)[off] = __float2bfloat16(v);
                else      ((float*)C)[off] = v;
            }
        }
    }
}

// ---------------------------------------------------------------------------
// MFMA flash attention. Block = 256 thr (4 waves) x 64 queries (16 q/wave);
// 8 KV-tiles of 128 keys. R1's proven staged structure (LDS K/V + barriers).
// Q A-frags in regs (Q pre-scaled by log2e/sqrt(E) -> softmax in exp2
// domain). Masked scores -1e30; running max starts at -1e29 so exp2
// underflows masked lanes to exactly 0.
//
// R4 trims (independent of structure):
//  * bitmask: 4 broadcast uint4 loads/tile instead of 32 scalar int loads
//  * l-sum cross-lane reduction deferred to epilogue (lS is a per-lane
//    partial; alpha is uniform within each 16-lane row group)
//  * T13 defer-max: skip alpha/rescale when no row grew by >8 (exp2 domain;
//    P bounded by 2^8, harmless in f32/bf16)
// ---------------------------------------------------------------------------
#define QT  64
#define KTL 128
#define NT  (TSEQ / KTL)   // 8
#define KP  72    // Ks pitch: [128 keys][64 d + 8 pad]
#define VP  136   // Vs pitch: [64 d][128 keys + 8 pad]
#define PP  136   // Ps pitch: per wave [16 q][128 keys + 8 pad]

__global__ __launch_bounds__(256) void attn_mfma(
    const __hip_bfloat16* __restrict__ Q,
    const __hip_bfloat16* __restrict__ K,
    const __hip_bfloat16* __restrict__ Vt,
    const int* __restrict__ mask,
    const unsigned* __restrict__ bmask,
    __hip_bfloat16* __restrict__ O)
{
    __shared__ __hip_bfloat16 Ks[KTL * KP];
    __shared__ __hip_bfloat16 Vs[HD * VP];
    __shared__ __hip_bfloat16 Ps[4][16 * PP];

    const int tid  = threadIdx.x;
    const int lane = tid & 63;
    const int w    = tid >> 6;
    const int fr   = lane & 15;
    const int fq   = lane >> 4;
    const int qb = blockIdx.x, h = blockIdx.y, b = blockIdx.z;
    const int q0 = qb * QT;

    // Q A-frags: A[m = lane&15][k = fq*8 + j], k-chunks 0 and 32
    const __hip_bfloat16* qptr =
        Q + (size_t)(b * TSEQ + q0 + w * 16 + fr) * EMBED + h * HD + fq * 8;
    const bf16x8 qa0 = *(const bf16x8*)qptr;
    const bf16x8 qa1 = *(const bf16x8*)(qptr + 32);

    // bitmask row base (words; row = b*TSEQ + q0 + w*16 + fq*4 + r)
    const unsigned* bmbase = bmask
        ? bmask + (size_t)(b * TSEQ + q0 + w * 16 + fq * 4) * (TSEQ / 32)
        : nullptr;

    float mS[4], lS[4];
    f32x4 oacc[4];
#pragma unroll
    for (int r = 0; r < 4; ++r) { mS[r] = -1e29f; lS[r] = 0.f; }
#pragma unroll
    for (int dt = 0; dt < 4; ++dt) oacc[dt] = (f32x4){0.f, 0.f, 0.f, 0.f};

    for (int kt = 0; kt < NT; ++kt) {
        __syncthreads();
        // stage K tile [128 keys][64 d] and Vt tile [64 d][128 keys]
#pragma unroll
        for (int i = 0; i < 4; ++i) {
            const int cc  = tid + 256 * i;        // 0..1023
            const int key = cc >> 3;
            const int dc  = (cc & 7) * 8;
            *(uint4*)&Ks[key * KP + dc] = *(const uint4*)(
                K + (size_t)(b * TSEQ + kt * KTL + key) * EMBED + h * HD + dc);
            const int d  = cc >> 4;
            const int kc = (cc & 15) * 8;
            *(uint4*)&Vs[d * VP + kc] = *(const uint4*)(
                Vt + ((size_t)(b * NH + h) * HD + d) * TSEQ + kt * KTL + kc);
        }
        __syncthreads();

        // mask words: 4 broadcast uint4 loads (bitmask) or legacy int loads
        uint4 mw[4];
        int mvf[8][4];
        if (bmask) {
#pragma unroll
            for (int r = 0; r < 4; ++r)
                mw[r] = *(const uint4*)(bmbase + (size_t)r * (TSEQ / 32) + kt * 4);
        } else {
            const int* mbase = mask +
                (size_t)(b * TSEQ + q0 + w * 16 + fq * 4) * TSEQ + kt * KTL + fr;
#pragma unroll
            for (int t = 0; t < 8; ++t)
#pragma unroll
                for (int r = 0; r < 4; ++r)
                    mvf[t][r] = mbase[r * TSEQ + t * 16];
        }

        // QK^T: S[16 q][128 keys] in 8 C-layout frags (exp2 domain)
        f32x4 s[8];
#pragma unroll
        for (int t = 0; t < 8; ++t) {
            const bf16x8 kb0 = *(const bf16x8*)&Ks[(t * 16 + fr) * KP + fq * 8];
            const bf16x8 kb1 = *(const bf16x8*)&Ks[(t * 16 + fr) * KP + 32 + fq * 8];
            s[t] = __builtin_amdgcn_mfma_f32_16x16x32_bf16(
                qa0, kb0, (f32x4){0.f, 0.f, 0.f, 0.f}, 0, 0, 0);
            s[t] = __builtin_amdgcn_mfma_f32_16x16x32_bf16(qa1, kb1, s[t], 0, 0, 0);
        }

        // mask (scale already folded into Q)
        if (bmask) {
#pragma unroll
            for (int t = 0; t < 8; ++t)
#pragma unroll
                for (int r = 0; r < 4; ++r) {
                    const unsigned wv = ((const unsigned*)&mw[r])[t >> 1] >> fr;
                    if (((wv >> ((t & 1) * 16)) & 1u) == 0u) s[t][r] = -1e30f;
                }
        } else {
#pragma unroll
            for (int t = 0; t < 8; ++t)
#pragma unroll
                for (int r = 0; r < 4; ++r)
                    if (mvf[t][r] == 0) s[t][r] = -1e30f;
        }

        // per-row max (row = fq*4 + r; keys spread over 16 fr-lanes x 8 frags)
        float mx[4];
#pragma unroll
        for (int r = 0; r < 4; ++r) {
            float m = s[0][r];
#pragma unroll
            for (int t = 1; t < 8; ++t) m = fmaxf(m, s[t][r]);
#pragma unroll
            for (int off = 8; off > 0; off >>= 1) m = fmaxf(m, __shfl_xor(m, off));
            mx[r] = m;
        }

        // T13 defer-max: rescale only if some row grew by > 8 (exp2 domain)
        float dmax = mx[0] - mS[0];
#pragma unroll
        for (int r = 1; r < 4; ++r) dmax = fmaxf(dmax, mx[r] - mS[r]);
        if (__any(dmax > 8.f)) {
#pragma unroll
            for (int r = 0; r < 4; ++r) {
                const float mnew  = fmaxf(mS[r], mx[r]);
                const float alpha = __builtin_amdgcn_exp2f(mS[r] - mnew);
                mS[r] = mnew;
                lS[r] *= alpha;
#pragma unroll
                for (int dt = 0; dt < 4; ++dt) oacc[dt][r] *= alpha;
            }
        }

        // p = exp2(s - mS); lS accumulates a PER-LANE partial (reduced in
        // the epilogue -- saves a 4-step shfl chain per row per tile)
#pragma unroll
        for (int r = 0; r < 4; ++r) {
            float ls = 0.f;
#pragma unroll
            for (int t = 0; t < 8; ++t) {
                const float p = __builtin_amdgcn_exp2f(s[t][r] - mS[r]);
                s[t][r] = p;
                ls += p;
            }
            lS[r] += ls;
        }

        // P -> per-wave LDS (C-layout scatter), then A-layout b128 reads
#pragma unroll
        for (int t = 0; t < 8; ++t)
#pragma unroll
            for (int r = 0; r < 4; ++r)
                Ps[w][(fq * 4 + r) * PP + t * 16 + fr] = __float2bfloat16(s[t][r]);

        // PV: O[16 q][64 d] += P[16][128] x V[128][64]
#pragma unroll
        for (int kc = 0; kc < 4; ++kc) {
            const bf16x8 pa = *(const bf16x8*)&Ps[w][fr * PP + kc * 32 + fq * 8];
#pragma unroll
            for (int dt = 0; dt < 4; ++dt) {
                const bf16x8 vb =
                    *(const bf16x8*)&Vs[(dt * 16 + fr) * VP + kc * 32 + fq * 8];
                oacc[dt] = __builtin_amdgcn_mfma_f32_16x16x32_bf16(
                    pa, vb, oacc[dt], 0, 0, 0);
            }
        }
    }

    // epilogue: reduce lS across the 16 fr-lanes, normalize, write O
    float inv[4];
#pragma unroll
    for (int r = 0; r < 4; ++r) {
#pragma unroll
        for (int off = 8; off > 0; off >>= 1) lS[r] += __shfl_xor(lS[r], off);
        inv[r] = 1.f / fmaxf(lS[r], 1e-30f);
    }
#pragma unroll
    for (int dt = 0; dt < 4; ++dt)
#pragma unroll
        for (int r = 0; r < 4; ++r)
            O[(size_t)(b * TSEQ + q0 + w * 16 + fq * 4 + r) * EMBED
              + h * HD + dt * 16 + fr] = __float2bfloat16(oacc[dt][r] * inv[r]);
}

// ---------------------------------------------------------------------------
// Memory plan:
//   ws:    [Q | K] bf16 (64 MiB) | optional Wb[4] bf16 (8 MiB) | (bm spill)
//   d_out: [Vt bf16 32 MiB | Xb bf16 32 MiB]; after the V-GEMM Xb is dead and
//          pack_mask reuses its first 2 MiB for the bitmask. Final GEMM
//          overwrites d_out with the f32 result.
// ---------------------------------------------------------------------------
static inline void launch_gemm(int ad, int bd, dim3 g, dim3 b, hipStream_t s,
                               const void* A, const void* W, void* C,
                               const void* bias, const unsigned int* Xdet,
                               int a_flex, int out_mode, float cs)
{
    if (ad && bd)
        gemm_t<1, 1><<<g, b, 0, s>>>(A, W, C, bias, Xdet, a_flex, out_mode, cs);
    else if (ad)
        gemm_t<1, 0><<<g, b, 0, s>>>(A, W, C, bias, Xdet, a_flex, out_mode, cs);
    else if (bd)
        gemm_t<0, 1><<<g, b, 0, s>>>(A, W, C, bias, Xdet, a_flex, out_mode, cs);
    else
        gemm_t<0, 0><<<g, b, 0, s>>>(A, W, C, bias, Xdet, a_flex, out_mode, cs);
}

extern "C" void kernel_launch(void* const* d_in, const int* in_sizes, int n_in,
                              void* d_out, int out_size, void* d_ws, size_t ws_size,
                              hipStream_t stream) {
    const void* X  = d_in[0];
    const int*  Mk = (const int*)d_in[1];
    const void* Wsrc[4] = { d_in[2], d_in[3], d_in[4], d_in[5] };
    const void* bo = d_in[6];
    const unsigned int* Xdet = (const unsigned int*)d_in[0];

    const size_t n_elem = (size_t)MROWS * EMBED;    // 16 Mi elems
    const size_t w_elem = (size_t)EMBED * EMBED;    // 1 Mi elems
    __hip_bfloat16* Qb  = (__hip_bfloat16*)d_ws;    // ws: Q | K
    __hip_bfloat16* Kb  = Qb + n_elem;
    __hip_bfloat16* Vtb = (__hip_bfloat16*)d_out;   // V^T in d_out lower half
    size_t ws_used = 2 * n_elem * sizeof(__hip_bfloat16);

    dim3 blk(256);

    // --- A operand (X): normalize to bf16 once if we have room ---
    const void* Ax = X;
    int ad = 0;
    if (in_sizes[0] == (int)(n_elem * 2)) {
        ad = 1;                                      // already bf16-sized
    } else {
        __hip_bfloat16* Xb = nullptr;
        if ((size_t)out_size >= n_elem * 4) {
            Xb = (__hip_bfloat16*)d_out + n_elem;    // d_out upper half
        } else if (ws_size >= ws_used + n_elem * 2) {
            Xb = (__hip_bfloat16*)((char*)d_ws + ws_used);
            ws_used += n_elem * 2;
        }
        if (Xb) {
            to_bf16<<<dim3((unsigned)(n_elem / 8 / 256)), blk, 0, stream>>>(
                X, Xb, (int)(n_elem / 8), Xdet);
            Ax = Xb;
            ad = 1;
        }
    }

    // --- B operands (W): normalize to bf16 once if ws has room ---
    const void* Wb[4];
    int bd = 0;
    if (in_sizes[2] == (int)(w_elem * 2)) {
        for (int i = 0; i < 4; ++i) Wb[i] = Wsrc[i];
        bd = 1;
    } else if (ws_size >= ws_used + 4 * w_elem * 2) {
        __hip_bfloat16* p = (__hip_bfloat16*)((char*)d_ws + ws_used);
        for (int i = 0; i < 4; ++i) {
            to_bf16<<<dim3((unsigned)(w_elem / 8 / 256)), blk, 0, stream>>>(
                Wsrc[i], p + (size_t)i * w_elem, (int)(w_elem / 8), Xdet);
            Wb[i] = p + (size_t)i * w_elem;
        }
        ws_used += 4 * w_elem * 2;
        bd = 1;
    } else {
        for (int i = 0; i < 4; ++i) Wb[i] = Wsrc[i];
    }

    // --- bitmask buffer: dead-Xb region of d_out, else ws tail ---
    const size_t bm_words = (size_t)NB * TSEQ * (TSEQ / 32);   // 512 Ki words
    const size_t bm_bytes = bm_words * 4;                      // 2 MiB
    unsigned* bm = nullptr;
    if ((size_t)out_size >= n_elem * 2 + bm_bytes) {
        bm = (unsigned*)((char*)d_out + n_elem * 2);           // dead-Xb start
    } else if (ws_size >= ws_used + bm_bytes) {
        bm = (unsigned*)((char*)d_ws + ws_used);
        ws_used += bm_bytes;
    }

    // grid: x = n-tiles (8), y = m-tiles (128) -> A-panel shared by
    // consecutive blocks
    dim3 gg(EMBED / 128, MROWS / 128, 1);
    // fold softmax scale (1/sqrt(1024)) * log2(e) into Q projection
    const float qs = 0.03125f * 1.44269504088896f;
    launch_gemm(ad, bd, gg, blk, stream, Ax, Wb[0], Qb,  nullptr, Xdet, 1, 0, qs);
    launch_gemm(ad, bd, gg, blk, stream, Ax, Wb[1], Kb,  nullptr, Xdet, 1, 0, 1.f);
    launch_gemm(ad, bd, gg, blk, stream, Ax, Wb[2], Vtb, nullptr, Xdet, 1, 2, 1.f);

    // pack mask AFTER the V-GEMM (it overwrites the start of dead Xb)
    if (bm) {
        const int nmask = NB * TSEQ * TSEQ;                    // 16.7M
        pack_mask<<<dim3(nmask / 256), blk, 0, stream>>>(Mk, bm, nmask);
    }

    dim3 ga(TSEQ / QT, NH, NB);                      // 16 x 16 x 16
    attn_mfma<<<ga, blk, 0, stream>>>(Qb, Kb, Vtb, Mk, bm, Qb);

    // final GEMM: A = attention output (bf16 in ws) -> always direct
    launch_gemm(1, bd, gg, blk, stream, Qb, Wb[3], d_out, bo, Xdet, 0, 1, 1.f);
}